// Round 4
// baseline (23847.406 us; speedup 1.0000x reference)
//
#include <hip/hip_runtime.h>
#include <cstdint>

typedef unsigned short u16;
typedef unsigned int u32;
typedef __attribute__((ext_vector_type(4))) float f32x4;
typedef __attribute__((ext_vector_type(8))) short short8;
typedef __attribute__((ext_vector_type(4))) short short4_t;
typedef __attribute__((ext_vector_type(4))) u32 u32x4;

#define DEV static __device__ __forceinline__

DEV u16 f2bf(float f) {
  union { float f; u32 u; } v; v.f = f;
  u32 r = v.u + 0x7fffu + ((v.u >> 16) & 1u);
  return (u16)(r >> 16);
}
DEV float bf2f(u16 b) {
  union { u32 u; float f; } v; v.u = ((u32)b) << 16; return v.f;
}
DEV float sigm(float x) { return 1.f / (1.f + __expf(-x)); }
DEV float tanhf_fast(float x) {
  float ax = fabsf(x);
  float e = __expf(-2.f * ax);
  float t = (1.f - e) / (1.f + e);
  return x < 0.f ? -t : t;
}

#define GLD_LDS16(g, l) __builtin_amdgcn_global_load_lds( \
    (const __attribute__((address_space(1))) u32*)(g),    \
    (__attribute__((address_space(3))) u32*)(l), 16, 0, 0)

// ---------------------------------------------------------------- utilities
__global__ __launch_bounds__(256) void zero_kernel(u32* __restrict__ p, int n) {
  int i = blockIdx.x * 256 + threadIdx.x;
  if (i < n) p[i] = 0u;
}

// diagnostic fallback: out = x + 1000 (signals "ws_size too small")
__global__ __launch_bounds__(256) void diag_kernel(const float* __restrict__ x,
                                                   float* __restrict__ o, int n) {
  int i = blockIdx.x * 256 + threadIdx.x;
  if (i < n) o[i] = x[i] + 1000.0f;
}

__global__ __launch_bounds__(256) void cvt_bf16_kernel(const float* __restrict__ src,
                                                       u16* __restrict__ dst, int n4) {
  int i = blockIdx.x * 256 + threadIdx.x;
  if (i < n4) {
    float4 v = ((const float4*)src)[i];
    short4_t o;
    o[0] = (short)f2bf(v.x); o[1] = (short)f2bf(v.y);
    o[2] = (short)f2bf(v.z); o[3] = (short)f2bf(v.w);
    ((short4_t*)dst)[i] = o;
  }
}

// ------------------------------------------------------------------- LN
// One block per token. Computes both norms (shared mean/var). which&1 ->
// write a0 (natural order), which&2 -> write a1 (L-flipped). bf16 dwords.
__global__ __launch_bounds__(256) void ln_kernel(const float* __restrict__ x,
    const float* __restrict__ w1, const float* __restrict__ b1,
    const float* __restrict__ w2, const float* __restrict__ b2,
    u32* __restrict__ a0, u32* __restrict__ a1, int which) {
  int tok = blockIdx.x;
  int tid = threadIdx.x, lane = tid & 63, wv = tid >> 6;
  __shared__ float ssum[4], ssq[4];
  __shared__ float smu, srstd;
  float2 v = ((const float2*)x)[(size_t)tok * 256 + tid];
  float s = v.x + v.y, q = v.x * v.x + v.y * v.y;
  for (int off = 32; off; off >>= 1) { s += __shfl_down(s, off); q += __shfl_down(q, off); }
  if (lane == 0) { ssum[wv] = s; ssq[wv] = q; }
  __syncthreads();
  if (tid == 0) {
    float S = ssum[0] + ssum[1] + ssum[2] + ssum[3];
    float Q = ssq[0] + ssq[1] + ssq[2] + ssq[3];
    float mu = S * (1.f / 512.f);
    float var = Q * (1.f / 512.f) - mu * mu;
    smu = mu; srstd = rsqrtf(var + 1e-5f);
  }
  __syncthreads();
  float mu = smu, rs = srstd;
  int d = tid * 2;
  float n0 = (v.x - mu) * rs, n1 = (v.y - mu) * rs;
  if (which & 1) {
    float o0 = n0 * w1[d] + b1[d], o1 = n1 * w1[d + 1] + b1[d + 1];
    a0[(size_t)tok * 256 + tid] = (u32)f2bf(o0) | ((u32)f2bf(o1) << 16);
  }
  if (which & 2) {
    float p0 = n0 * w2[d] + b2[d], p1 = n1 * w2[d + 1] + b2[d + 1];
    int b = tok >> 11, l = tok & 2047;
    size_t ftok = (size_t)(b << 11) + (2047 - l);
    a1[ftok * 256 + tid] = (u32)f2bf(p0) | ((u32)f2bf(p1) << 16);
  }
}

// ------------------------------------------------------------- conv + silu
// depthwise causal conv K=4 over L on bf16 [16384][1024]; 2 tokens / block.
__global__ __launch_bounds__(256) void conv_silu_kernel(const u16* __restrict__ xin,
    const float* __restrict__ cw, const float* __restrict__ cb, u16* __restrict__ yout) {
  __shared__ float wl[4096];
  __shared__ float bl[1024];
  int tid = threadIdx.x;
  for (int i = tid; i < 4096; i += 256) wl[i] = cw[i];
  for (int i = tid; i < 1024; i += 256) bl[i] = cb[i];
  __syncthreads();
  int tok = blockIdx.x * 2 + (tid >> 7);
  int c8 = (tid & 127) * 8;
  int l = tok & 2047;
  float accv[8];
#pragma unroll
  for (int j = 0; j < 8; ++j) accv[j] = bl[c8 + j];
#pragma unroll
  for (int k = 0; k < 4; ++k) {
    int dl = l - 3 + k;
    if (dl < 0) continue;
    short8 v = *(const short8*)(xin + (size_t)(tok - 3 + k) * 1024 + c8);
#pragma unroll
    for (int j = 0; j < 8; ++j)
      accv[j] += bf2f((u16)v[j]) * wl[(c8 + j) * 4 + k];
  }
  short8 o;
#pragma unroll
  for (int j = 0; j < 8; ++j) {
    float a = accv[j];
    o[j] = (short)f2bf(a * sigm(a));
  }
  *(short8*)(yout + (size_t)tok * 1024 + c8) = o;
}

// ------------------------------------------------------------------- GEMM
// C[m][n] = sum_k A[m][k] * Bt[n][k]   (A: [M][K] bf16, Bt: [N][K] bf16)
// 128x128 tile, BK=32, 4 waves (2x2), 16x16x32 bf16 MFMA, global_load_lds,
// chunk-XOR LDS swizzle.  Epilogues:
//  EPI 0: split cols<1024 -> out0, else -> out1 (bf16, row stride 1024)
//  EPI 1: +bias, bf16 -> out0 (row stride 3072)
//  EPI 2: bf16 -> out0[drow*1024 + colOff + col], drow row-flipped if flip
//  EPI 3: f32 -> outf[row*512+col] + bias[col] + resid[row*512+col]
template <int EPI>
__global__ __launch_bounds__(256) void gemm_bt_kernel(
    const u16* __restrict__ A, const u16* __restrict__ Bw,
    int M, int N, int K,
    const float* __restrict__ bias,
    u16* __restrict__ out0, u16* __restrict__ out1,
    float* __restrict__ outf, const float* __restrict__ resid,
    int flip, int colOff) {
  __shared__ u16 As[128 * 32];
  __shared__ u16 Bs[128 * 32];
  const int tid = threadIdx.x;
  const int lane = tid & 63;
  const int wv = tid >> 6;
  const int wr = (wv >> 1) * 64, wc = (wv & 1) * 64;
  const int bm = blockIdx.x * 128, bn = blockIdx.y * 128;
  f32x4 acc[4][4] = {};
  const int r0 = tid >> 2;
  const int pc = tid & 3;

  for (int k0 = 0; k0 < K; k0 += 32) {
    __syncthreads();
#pragma unroll
    for (int i = 0; i < 2; ++i) {
      int rA = i * 64 + r0;
      int lc = pc ^ (rA & 3);
      const u16* gA = A + (size_t)(bm + rA) * K + k0 + lc * 8;
      GLD_LDS16(gA, As + (i * 4096 + wv * 1024) / 2);
      const u16* gB = Bw + (size_t)(bn + rA) * K + k0 + lc * 8;
      GLD_LDS16(gB, Bs + (i * 4096 + wv * 1024) / 2);
    }
    __syncthreads();
    const int kc = lane >> 4;
    short8 af[4], bfr[4];
#pragma unroll
    for (int m = 0; m < 4; ++m) {
      int row = wr + m * 16 + (lane & 15);
      af[m] = *(const short8*)((const char*)As + row * 64 + ((kc ^ (row & 3)) * 16));
    }
#pragma unroll
    for (int n = 0; n < 4; ++n) {
      int row = wc + n * 16 + (lane & 15);
      bfr[n] = *(const short8*)((const char*)Bs + row * 64 + ((kc ^ (row & 3)) * 16));
    }
#pragma unroll
    for (int m = 0; m < 4; ++m)
#pragma unroll
      for (int n = 0; n < 4; ++n)
        acc[m][n] = __builtin_amdgcn_mfma_f32_16x16x32_bf16(af[m], bfr[n], acc[m][n], 0, 0, 0);
  }

  // epilogue: C element (row=(lane>>4)*4+r, col=lane&15) within each 16x16 tile
  if (EPI == 0) {
#pragma unroll
    for (int n = 0; n < 4; ++n) {
      int col = bn + wc + n * 16 + (lane & 15);
      u16* dst = (col < 1024) ? out0 : out1;
      int cc = col & 1023;
#pragma unroll
      for (int m = 0; m < 4; ++m) {
        int rb = bm + wr + m * 16 + ((lane >> 4) * 4);
#pragma unroll
        for (int r = 0; r < 4; ++r)
          dst[(size_t)(rb + r) * 1024 + cc] = f2bf(acc[m][n][r]);
      }
    }
  } else if (EPI == 1) {
#pragma unroll
    for (int n = 0; n < 4; ++n) {
      int col = bn + wc + n * 16 + (lane & 15);
      float bv = bias[col];
#pragma unroll
      for (int m = 0; m < 4; ++m) {
        int rb = bm + wr + m * 16 + ((lane >> 4) * 4);
#pragma unroll
        for (int r = 0; r < 4; ++r)
          out0[(size_t)(rb + r) * 3072 + col] = f2bf(acc[m][n][r] + bv);
      }
    }
  } else if (EPI == 2) {
#pragma unroll
    for (int m = 0; m < 4; ++m) {
      int rb = bm + wr + m * 16 + ((lane >> 4) * 4);
#pragma unroll
      for (int r = 0; r < 4; ++r) {
        int row = rb + r;
        int drow = flip ? ((row & ~2047) | (2047 - (row & 2047))) : row;
#pragma unroll
        for (int n = 0; n < 4; ++n) {
          int col = bn + wc + n * 16 + (lane & 15);
          out0[(size_t)drow * 1024 + colOff + col] = f2bf(acc[m][n][r]);
        }
      }
    }
  } else {
#pragma unroll
    for (int n = 0; n < 4; ++n) {
      int col = bn + wc + n * 16 + (lane & 15);
      float bv = bias[col];
#pragma unroll
      for (int m = 0; m < 4; ++m) {
        int rb = bm + wr + m * 16 + ((lane >> 4) * 4);
#pragma unroll
        for (int r = 0; r < 4; ++r) {
          size_t idx = (size_t)(rb + r) * 512 + col;
          outf[idx] = acc[m][n][r] + bv + resid[idx];
        }
      }
    }
  }
}

// -------------------------------------------------------------- GRU scan
// Persistent WGs (64/branch, 1/CU by LDS). WG owns 16 channels x 3 gates of
// whh in LDS. Per step: MFMA gh slice, fp32 gates, write h slice to a
// DOUBLE-BUFFERED coherent global h, counter barrier, restage full h.
// brsel < 0: grid 128, both branches (br = wg>>6). brsel >= 0: grid 64,
// single branch; gx/z/m pointers are then per-branch (strides 0).
__global__ __launch_bounds__(256, 1) void gru_scan_kernel(
    const u16* __restrict__ whh_bf,   // [2][3072][1024] always
    const float* __restrict__ bhh_f, const float* __restrict__ bhh_b,
    const u16* __restrict__ gx,       // [.][16384][3072]  (bih already added)
    const u16* __restrict__ zg,       // [.][16384][1024]
    u16* __restrict__ m_out,          // [.][16384][1024]
    u32* __restrict__ h_buf,          // [2 buf][2 br][4096 dwords]
    u32* __restrict__ counters,       // [2][2048]
    int brsel, size_t gxStride, size_t zStride)
{
  __shared__ u16 whh_lds[48 * 1024];           // 96 KB (swizzled)
  __shared__ u16 h_lds[16 * 1024];             // 32 KB (rows 8..15 zero)
  __shared__ float red[4][3][16][16];          // 12 KB
  __shared__ u32 stage[256];                   // gx (0..191) + z (192..255)
  __shared__ float bhh_lds[48];

  const int tid = threadIdx.x;
  const int lane = tid & 63, wv = tid >> 6;
  const int wg = blockIdx.x;
  int br, c0;
  if (brsel < 0) { br = wg >> 6; c0 = (wg & 63) * 16; }
  else           { br = brsel;   c0 = wg * 16; }

  const u16* whh = whh_bf + (size_t)br * 3072 * 1024;
  const float* bhh = br ? bhh_b : bhh_f;
  const u16* gxB = gx + (size_t)br * gxStride;
  const u16* zB = zg + (size_t)br * zStride;
  u16* mB = m_out + (size_t)br * zStride;
  u32* cnt = counters + br * 2048;

  // --- stage whh slice into LDS (XOR swizzle on 16B chunks within rows)
  for (int q = tid; q < 6144; q += 256) {
    int row = q >> 7;          // 0..47 = gate*16 + cl
    int kc = q & 127;
    int g = row >> 4, cl = row & 15;
    short8 v = *(const short8*)(whh + (size_t)(g * 1024 + c0 + cl) * 1024 + kc * 8);
    int byte = row * 2048 + ((kc * 16) ^ ((row & 7) << 4));
    *(short8*)((char*)whh_lds + byte) = v;
  }
  if (tid < 48) bhh_lds[tid] = bhh[(tid >> 4) * 1024 + c0 + (tid & 15)];
  // zero h_lds rows 8..15 (MFMA M-pad)
  for (int q = tid; q < 4096; q += 256) {
    int rowq = 8 + (q >> 9); int cp = q & 511;
    int byte = rowq * 2048 + ((cp * 4) ^ ((rowq & 7) << 4));
    *(u32*)((char*)h_lds + byte) = 0u;
  }
  __syncthreads();

  // prefetch roles (loop-invariant)
  int pfb = 0, pfg = 0, pfd = 0;
  if (tid < 192) { pfb = tid / 24; pfg = (tid >> 3) % 3; pfd = tid & 7; }
  else { int j = tid - 192; pfb = j >> 3; pfd = j & 7; }
  // prefetch t = 0
  u32 pf;
  if (tid < 192)
    pf = ((const u32*)(gxB + (size_t)(pfb * 2048 + 0) * 3072 + pfg * 1024 + c0))[pfd];
  else
    pf = ((const u32*)(zB + (size_t)(pfb * 2048 + 0) * 1024 + c0))[pfd];

  float h_state = 0.f;
  bool dead = false;                // deadlock guard latch (tid 0 only uses it)
  const int arow = lane & 15;
  const int kchunk = (lane >> 4) * 16;
  const int aswz = (arow & 7) << 4;
  const int a_base = arow * 2048;
  const int b0_base = arow * 2048;
  const int b1_base = (16 + arow) * 2048;
  const int b2_base = (32 + arow) * 2048;

  for (int t = 0; t < 2048; ++t) {
    // [A] wait for all h_{t-1} slices
    if (t > 0) {
      if (tid == 0 && !dead) {
        int guard = 0;
        while (__hip_atomic_load(&cnt[t - 1], __ATOMIC_ACQUIRE, __HIP_MEMORY_SCOPE_AGENT) < 64u) {
          __builtin_amdgcn_s_sleep(2);
          if (++guard > (1 << 27)) { dead = true; break; }  // bail instead of hanging
        }
      }
      __syncthreads();
    }
    // [B] restage full h (coherent, batched dwordx4), dump prefetch regs
    {
      const u32* hRead = h_buf + ((((t + 1) & 1) * 2 + br) * 4096);
      const u32* hp = hRead + tid * 16;
      u32x4 va, vb, vc, vd;
      asm volatile(
          "global_load_dwordx4 %0, %4, off sc0 sc1\n\t"
          "global_load_dwordx4 %1, %5, off sc0 sc1\n\t"
          "global_load_dwordx4 %2, %6, off sc0 sc1\n\t"
          "global_load_dwordx4 %3, %7, off sc0 sc1\n\t"
          "s_waitcnt vmcnt(0)"
          : "=&v"(va), "=&v"(vb), "=&v"(vc), "=&v"(vd)
          : "v"(hp), "v"(hp + 4), "v"(hp + 8), "v"(hp + 12)
          : "memory");
      int bq = tid >> 5;
      int base = bq * 2048 + (tid & 31) * 64;
      int swz = (bq & 7) << 4;
      *(u32x4*)((char*)h_lds + ((base + 0) ^ swz)) = va;
      *(u32x4*)((char*)h_lds + ((base + 16) ^ swz)) = vb;
      *(u32x4*)((char*)h_lds + ((base + 32) ^ swz)) = vc;
      *(u32x4*)((char*)h_lds + ((base + 48) ^ swz)) = vd;
      stage[tid] = pf;
    }
    __syncthreads();
    // [C] prefetch t+1; MFMA gh slice (K split over 4 waves)
    {
      int tn = (t + 1 < 2048) ? (t + 1) : 2047;
      if (tid < 192)
        pf = ((const u32*)(gxB + (size_t)(pfb * 2048 + tn) * 3072 + pfg * 1024 + c0))[pfd];
      else
        pf = ((const u32*)(zB + (size_t)(pfb * 2048 + tn) * 1024 + c0))[pfd];
    }
    f32x4 acc0 = {}, acc1 = {}, acc2 = {};
#pragma unroll
    for (int ks = 0; ks < 8; ++ks) {
      int kx = (wv * 512 + ks * 64 + kchunk) ^ aswz;
      short8 af = *(const short8*)((const char*)h_lds + a_base + kx);
      short8 b0 = *(const short8*)((const char*)whh_lds + b0_base + kx);
      short8 b1 = *(const short8*)((const char*)whh_lds + b1_base + kx);
      short8 b2 = *(const short8*)((const char*)whh_lds + b2_base + kx);
      acc0 = __builtin_amdgcn_mfma_f32_16x16x32_bf16(af, b0, acc0, 0, 0, 0);
      acc1 = __builtin_amdgcn_mfma_f32_16x16x32_bf16(af, b1, acc1, 0, 0, 0);
      acc2 = __builtin_amdgcn_mfma_f32_16x16x32_bf16(af, b2, acc2, 0, 0, 0);
    }
    {
      int col = lane & 15, r4 = (lane >> 4) * 4;
#pragma unroll
      for (int r = 0; r < 4; ++r) {
        red[wv][0][r4 + r][col] = acc0[r];
        red[wv][1][r4 + r][col] = acc1[r];
        red[wv][2][r4 + r][col] = acc2[r];
      }
    }
    __syncthreads();
    // [D] gates (threads 0..127: b = tid>>4, c = tid&15)
    if (tid < 128) {
      int b = tid >> 4, c = tid & 15;
      float ghr = red[0][0][b][c] + red[1][0][b][c] + red[2][0][b][c] + red[3][0][b][c] + bhh_lds[c];
      float ghz = red[0][1][b][c] + red[1][1][b][c] + red[2][1][b][c] + red[3][1][b][c] + bhh_lds[16 + c];
      float ghn = red[0][2][b][c] + red[1][2][b][c] + red[2][2][b][c] + red[3][2][b][c] + bhh_lds[32 + c];
      int sb = b * 24, half = c & 1, ci = c >> 1;
      u32 wr_ = stage[sb + ci];
      u32 wz_ = stage[sb + 8 + ci];
      u32 wn_ = stage[sb + 16 + ci];
      u32 wm_ = stage[192 + b * 8 + ci];
      float gxr = bf2f((u16)(half ? (wr_ >> 16) : wr_));
      float gxz = bf2f((u16)(half ? (wz_ >> 16) : wz_));
      float gxn = bf2f((u16)(half ? (wn_ >> 16) : wn_));
      float zmv = bf2f((u16)(half ? (wm_ >> 16) : wm_));
      float r = sigm(gxr + ghr);
      float zt = sigm(gxz + ghz);
      float nt = tanhf_fast(gxn + r * ghn);
      float h = (1.f - zt) * nt + zt * h_state;
      h_state = h;
      float mval = h * (zmv * sigm(zmv));
      u16 hb16 = f2bf(h), mb16 = f2bf(mval);
      u32 hbp = (u32)__shfl_xor((int)hb16, 1);
      u32 mbp = (u32)__shfl_xor((int)mb16, 1);
      if (!half) {
        u32 hw = (u32)hb16 | (hbp << 16);
        u32 mw = (u32)mb16 | (mbp << 16);
        u32* hWrite = h_buf + (((t & 1) * 2 + br) * 4096);
        __hip_atomic_store(&hWrite[(b * 1024 + c0 + c) >> 1], hw,
                           __ATOMIC_RELAXED, __HIP_MEMORY_SCOPE_AGENT);
        *(u32*)(mB + (size_t)(b * 2048 + t) * 1024 + c0 + c) = mw;
      }
    }
    __syncthreads();
    // [E] arrive
    if (tid == 0)
      __hip_atomic_fetch_add(&cnt[t], 1u, __ATOMIC_RELEASE, __HIP_MEMORY_SCOPE_AGENT);
  }
}

// ------------------------------------------------------------------ launch
extern "C" void kernel_launch(void* const* d_in, const int* in_sizes, int n_in,
                              void* d_out, int out_size, void* d_ws, size_t ws_size,
                              hipStream_t stream) {
  (void)in_sizes; (void)n_in; (void)out_size;
  const float* x = (const float*)d_in[0];
  const float* n1w = (const float*)d_in[1];
  const float* n1b = (const float*)d_in[2];
  const float* n2w = (const float*)d_in[3];
  const float* n2b = (const float*)d_in[4];
  const float* fusw = (const float*)d_in[5];
  const float* fusb = (const float*)d_in[6];
  const float* inpj[2] = {(const float*)d_in[7], (const float*)d_in[15]};
  const float* cwv[2] = {(const float*)d_in[8], (const float*)d_in[16]};
  const float* cbv[2] = {(const float*)d_in[9], (const float*)d_in[17]};
  const float* wihp[2] = {(const float*)d_in[10], (const float*)d_in[18]};
  const float* whhp[2] = {(const float*)d_in[11], (const float*)d_in[19]};
  const float* bihp[2] = {(const float*)d_in[12], (const float*)d_in[20]};
  const float* bhhp[2] = {(const float*)d_in[13], (const float*)d_in[21]};
  const float* outpp[2] = {(const float*)d_in[14], (const float*)d_in[22]};

  char* ws = (char*)d_ws;
  // ---- fixed weight block (both modes) ----
  constexpr size_t OFF_CNT = 0;                       // 16 KiB
  constexpr size_t OFF_HBUF = 16384;                  // 64 KiB
  constexpr size_t OFF_WINP = 81920;
  constexpr size_t SZ_WINP = (size_t)2 * 2048 * 512 * 2;       //  4 MiB
  constexpr size_t OFF_WIH = OFF_WINP + SZ_WINP;
  constexpr size_t SZ_WIH = (size_t)2 * 3072 * 1024 * 2;       // 12 MiB
  constexpr size_t OFF_WHH = OFF_WIH + SZ_WIH;
  constexpr size_t OFF_WOUT = OFF_WHH + SZ_WIH;
  constexpr size_t SZ_WOUT = (size_t)2 * 512 * 1024 * 2;
  constexpr size_t OFF_WFUS = OFF_WOUT + SZ_WOUT;
  constexpr size_t SZ_WFUS = (size_t)512 * 1024 * 2;
  constexpr size_t SZ_W = OFF_WFUS + SZ_WFUS;                  // 32,587,776

  constexpr size_t SZ_HALF = (size_t)16384 * 1024 * 2;         // 33,554,432
  constexpr size_t SZ_PAIR = 2 * SZ_HALF;                      // 67,108,864
  constexpr size_t SZ_GX1 = (size_t)16384 * 3072 * 2;          // 100,663,296
  constexpr size_t SZ_GX2 = 2 * SZ_GX1;                        // 201,326,592
  constexpr size_t SZ_ALN2 = (size_t)2 * 16384 * 512 * 2;      // 33,554,432

  constexpr size_t NEED_A = SZ_W + 3 * SZ_PAIR + SZ_GX2;       // 435,240,960
  constexpr size_t NEED_B = SZ_W + SZ_GX1 + 4 * SZ_HALF;       // 267,468,800

  if (ws_size < NEED_B) {  // can't run at all: emit diagnostic signature
    diag_kernel<<<32768, 256, 0, stream>>>(x, (float*)d_out, 8388608);
    return;
  }

  u32* cnt = (u32*)(ws + OFF_CNT);
  u32* hbuf = (u32*)(ws + OFF_HBUF);
  u16* wInp = (u16*)(ws + OFF_WINP);
  u16* wWih = (u16*)(ws + OFF_WIH);
  u16* wWhh = (u16*)(ws + OFF_WHH);
  u16* wOut = (u16*)(ws + OFF_WOUT);
  u16* wFus = (u16*)(ws + OFF_WFUS);

  zero_kernel<<<80, 256, 0, stream>>>(cnt, 20480);  // counters + h_buf

  cvt_bf16_kernel<<<1024, 256, 0, stream>>>(inpj[0], wInp, 262144);
  cvt_bf16_kernel<<<1024, 256, 0, stream>>>(inpj[1], wInp + 1048576, 262144);
  cvt_bf16_kernel<<<3072, 256, 0, stream>>>(wihp[0], wWih, 786432);
  cvt_bf16_kernel<<<3072, 256, 0, stream>>>(wihp[1], wWih + 3145728, 786432);
  cvt_bf16_kernel<<<3072, 256, 0, stream>>>(whhp[0], wWhh, 786432);
  cvt_bf16_kernel<<<3072, 256, 0, stream>>>(whhp[1], wWhh + 3145728, 786432);
  cvt_bf16_kernel<<<512, 256, 0, stream>>>(outpp[0], wOut, 131072);
  cvt_bf16_kernel<<<512, 256, 0, stream>>>(outpp[1], wOut + 524288, 131072);
  cvt_bf16_kernel<<<512, 256, 0, stream>>>(fusw, wFus, 131072);

  if (ws_size >= NEED_A) {
    // ================= Mode A: concurrent dual-branch scan (415 MiB) ====
    char* RP = ws + SZ_W;            // convin[2] -> m[2]
    char* RQ = RP + SZ_PAIR;         // y[2] -> comb
    char* RZ = RQ + SZ_PAIR;         // z[2]
    char* RG = RZ + SZ_PAIR;         // gx[2]; aln[2] at tail
    u16* aln = (u16*)(RG + SZ_GX2 - SZ_ALN2);

    ln_kernel<<<16384, 256, 0, stream>>>(x, n1w, n1b, n2w, n2b,
        (u32*)aln, (u32*)(aln + (size_t)16384 * 512), 3);

    for (int br = 0; br < 2; ++br) {
      gemm_bt_kernel<0><<<dim3(128, 16), 256, 0, stream>>>(
          aln + (size_t)br * 16384 * 512, wInp + (size_t)br * 1048576,
          16384, 2048, 512, nullptr,
          (u16*)(RP + br * SZ_HALF), (u16*)(RZ + br * SZ_HALF),
          nullptr, nullptr, 0, 0);
      conv_silu_kernel<<<8192, 256, 0, stream>>>(
          (u16*)(RP + br * SZ_HALF), cwv[br], cbv[br], (u16*)(RQ + br * SZ_HALF));
      gemm_bt_kernel<1><<<dim3(128, 24), 256, 0, stream>>>(
          (u16*)(RQ + br * SZ_HALF), wWih + (size_t)br * 3145728,
          16384, 3072, 1024, bihp[br],
          (u16*)(RG + br * SZ_GX1), nullptr, nullptr, nullptr, 0, 0);
    }

    gru_scan_kernel<<<128, 256, 0, stream>>>(wWhh, bhhp[0], bhhp[1],
        (const u16*)RG, (const u16*)RZ, (u16*)RP, hbuf, cnt,
        -1, (size_t)16384 * 3072, (size_t)16384 * 1024);

    for (int br = 0; br < 2; ++br) {
      gemm_bt_kernel<2><<<dim3(128, 4), 256, 0, stream>>>(
          (u16*)(RP + br * SZ_HALF), wOut + (size_t)br * 524288,
          16384, 512, 1024, nullptr,
          (u16*)RQ, nullptr, nullptr, nullptr, br, br * 512);
    }

    gemm_bt_kernel<3><<<dim3(128, 4), 256, 0, stream>>>(
        (u16*)RQ, wFus, 16384, 512, 1024, fusb,
        nullptr, nullptr, (float*)d_out, x, 0, 0);
  } else {
    // ============ Mode B: sequential per-branch pipeline (255 MiB) ======
    char* RG = ws + SZ_W;            // gx (one branch)
    char* RZ = RG + SZ_GX1;          // z (one branch)
    char* RC = RZ + SZ_HALF;         // convin -> m
    char* RY = RC + SZ_HALF;         // aln_br -> y
    char* RB = RY + SZ_HALF;         // comb

    for (int br = 0; br < 2; ++br) {
      ln_kernel<<<16384, 256, 0, stream>>>(x, n1w, n1b, n2w, n2b,
          (u32*)RY, (u32*)RY, br ? 2 : 1);
      gemm_bt_kernel<0><<<dim3(128, 16), 256, 0, stream>>>(
          (u16*)RY, wInp + (size_t)br * 1048576,
          16384, 2048, 512, nullptr,
          (u16*)RC, (u16*)RZ, nullptr, nullptr, 0, 0);
      conv_silu_kernel<<<8192, 256, 0, stream>>>(
          (u16*)RC, cwv[br], cbv[br], (u16*)RY);
      gemm_bt_kernel<1><<<dim3(128, 24), 256, 0, stream>>>(
          (u16*)RY, wWih + (size_t)br * 3145728,
          16384, 3072, 1024, bihp[br],
          (u16*)RG, nullptr, nullptr, nullptr, 0, 0);
      gru_scan_kernel<<<64, 256, 0, stream>>>(wWhh, bhhp[0], bhhp[1],
          (const u16*)RG, (const u16*)RZ, (u16*)RC, hbuf, cnt,
          br, 0, 0);
      gemm_bt_kernel<2><<<dim3(128, 4), 256, 0, stream>>>(
          (u16*)RC, wOut + (size_t)br * 524288,
          16384, 512, 1024, nullptr,
          (u16*)RB, nullptr, nullptr, nullptr, br, br * 512);
    }

    gemm_bt_kernel<3><<<dim3(128, 4), 256, 0, stream>>>(
        (u16*)RB, wFus, 16384, 512, 1024, fusb,
        nullptr, nullptr, (float*)d_out, x, 0, 0);
  }
}